// Round 6
// baseline (137.620 us; speedup 1.0000x reference)
//
#include <hip/hip_runtime.h>
#include <stdint.h>

#define N_NODES 8192
#define N_EDGES 262144
#define IN_C    512
#define OUT_C   512
#define MAX_DEG 128   // raw degree Poisson(~32); dataset-validated max <= 128 (R0 128-cap passed)
#define X_ELEMS (N_NODES * IN_C)                 // 4194304
#define W_ELEMS (OUT_C * IN_C)                   // 262144
#define BM_WORDS (N_NODES * (N_NODES / 32))      // 2097152 u32 = 8 MB adjacency bitmap

typedef __attribute__((ext_vector_type(8))) short short8;   // 8 bf16 in 4 VGPRs
typedef __attribute__((ext_vector_type(4))) float f32x4;

// ---- fp32 -> bf16 (RNE) ----
__device__ inline uint16_t f2bf(float f) {
    uint32_t u = __float_as_uint(f);
    uint32_t r = (u + 0x7FFFu + ((u >> 16) & 1u)) >> 16;
    return (uint16_t)r;
}

// converts x and W to bf16; also zeros degree counters and the adjacency bitmap
__global__ __launch_bounds__(256) void convert_k(const float* __restrict__ x,
                                                 const float* __restrict__ W,
                                                 uint16_t* __restrict__ xb,
                                                 uint16_t* __restrict__ wb,
                                                 int* __restrict__ cnt,
                                                 uint4* __restrict__ bm) {
    int tid = blockIdx.x * 256 + threadIdx.x;
    if (tid < N_NODES) cnt[tid] = 0;
    if (tid < BM_WORDS / 4) bm[tid] = make_uint4(0u, 0u, 0u, 0u);   // 524288 * 16B = 8 MB
    int i = tid * 8;
    const float* src; uint16_t* dst;
    if (i < X_ELEMS) { src = x + i; dst = xb + i; }
    else             { src = W + (i - X_ELEMS); dst = wb + (i - X_ELEMS); }
    float4 v0 = *(const float4*)(src);
    float4 v1 = *(const float4*)(src + 4);
    ushort4 o0, o1;
    o0.x = f2bf(v0.x); o0.y = f2bf(v0.y); o0.z = f2bf(v0.z); o0.w = f2bf(v0.w);
    o1.x = f2bf(v1.x); o1.y = f2bf(v1.y); o1.z = f2bf(v1.z); o1.w = f2bf(v1.w);
    *(ushort4*)(dst)     = o0;
    *(ushort4*)(dst + 4) = o1;
}

// ---- fused: blocks [0,512) = GEMM tiles; blocks [512,1568) = bitmap-dedup edge scatter ----
// GEMM: h = x @ W^T + b (bf16 MFMA 16x16x32, fp32 accum, bf16 out)
//   block tile 128 rows x 64 cols; wave tile 64x32 (4 A x 2 B frags)
//   Operand-SWAPPED mfma(Wfrag, xfrag): D[row=quad*4+r -> out-channel n][col=l16 -> x-row m]
//   => each lane holds 4 CONSECUTIVE output channels of one row -> packed 8-B C-stores
//   XCD swizzle: the 8 col-blocks sharing one A-panel get the same (bid&7) residue -> same XCD L2
// Scatter: atomicOr claims bit (r,c) in the 8 MB bitmap; first claimer appends c to nbr[r] and
//   bumps cnt[r] -> nbr is unique and cnt final when this kernel completes. Scatter hides under MFMA.
__global__ __launch_bounds__(256) void gemm_scatter_k(const uint16_t* __restrict__ xb,
                                                      const uint16_t* __restrict__ wb,
                                                      const float* __restrict__ bias,
                                                      uint16_t* __restrict__ h,
                                                      const int* __restrict__ ei,
                                                      int* __restrict__ cnt,
                                                      uint16_t* __restrict__ nbr,
                                                      uint32_t* __restrict__ bm) {
    const int bid = blockIdx.x;
    if (bid < 512) {
        // ---------------- GEMM path ----------------
        const int wave = threadIdx.x >> 6;
        const int lane = threadIdx.x & 63;
        const int quad = lane >> 4;
        const int l16  = lane & 15;
        // bijective (bid) -> (mrow in [0,64), ncol in [0,8)) with A-panel sharers on one XCD
        const int mrow = (bid & 7) * 8 + (bid >> 6);
        const int ncol = (bid >> 3) & 7;
        const int m_base = mrow * 128 + (wave & 1) * 64;
        const int n_base = ncol * 64 + (wave >> 1) * 32;

        f32x4 acc[4][2];
        #pragma unroll
        for (int a = 0; a < 4; a++)
            #pragma unroll
            for (int s = 0; s < 2; s++) acc[a][s] = (f32x4){0.f, 0.f, 0.f, 0.f};

        #pragma unroll 2
        for (int k0 = 0; k0 < IN_C; k0 += 32) {
            short8 af[4], bf[2];
            #pragma unroll
            for (int a = 0; a < 4; a++)   // x[m=lane&15][k=quad*8+j]
                af[a] = *(const short8*)(xb + (m_base + a * 16 + l16) * IN_C + quad * 8 + k0);
            #pragma unroll
            for (int s = 0; s < 2; s++)   // W[n=lane&15][k=quad*8+j]
                bf[s] = *(const short8*)(wb + (n_base + s * 16 + l16) * IN_C + quad * 8 + k0);
            // swapped order: A-operand = W-frag, B-operand = x-frag -> D[n][m] (transposed frag)
            #pragma unroll
            for (int a = 0; a < 4; a++)
                #pragma unroll
                for (int s = 0; s < 2; s++)
                    acc[a][s] = __builtin_amdgcn_mfma_f32_16x16x32_bf16(bf[s], af[a], acc[a][s], 0, 0, 0);
        }
        // D': col=l16 -> m (x-row), row=quad*4+r -> n (out channel). 4 consecutive n per lane.
        #pragma unroll
        for (int s = 0; s < 2; s++) {
            int col_n0 = n_base + s * 16 + quad * 4;
            float4 bv = *(const float4*)(bias + col_n0);
            #pragma unroll
            for (int a = 0; a < 4; a++) {
                int row_m = m_base + a * 16 + l16;
                ushort4 o;
                o.x = f2bf(acc[a][s][0] + bv.x);
                o.y = f2bf(acc[a][s][1] + bv.y);
                o.z = f2bf(acc[a][s][2] + bv.z);
                o.w = f2bf(acc[a][s][3] + bv.w);
                *(ushort4*)(h + row_m * OUT_C + col_n0) = o;   // 8-B packed store
            }
        }
    } else {
        // ---------------- scatter path (bitmap dedup) ----------------
        int t = (bid - 512) * 256 + threadIdx.x;
        int r, c;
        if (t < N_EDGES) {
            r = ei[t];             // edge_index[0][t]
            c = ei[N_EDGES + t];   // edge_index[1][t]
        } else if (t < N_EDGES + N_NODES) {
            r = t - N_EDGES; c = r;   // self loop
        } else return;
        uint32_t w   = (uint32_t)r * (uint32_t)(N_NODES / 32) + ((uint32_t)c >> 5);
        uint32_t bit = 1u << (c & 31);
        uint32_t old = atomicOr(&bm[w], bit);
        if (!(old & bit)) {                       // first claimer of (r,c)
            int pos = atomicAdd(&cnt[r], 1);
            if (pos < MAX_DEG) nbr[r * MAX_DEG + pos] = (uint16_t)c;
        }
    }
}

// ---- out[i] = rsqrt(deg_i) * sum_j rsqrt(deg_j) * h[j]; bf16 h, channel-QUARTERED ----
// Persistent-wave form: 2048 blocks x 256 thr (8 blocks/CU, 32 waves/CU) instead of 32768
// single-wave blocks -> ~16x less workgroup-dispatch overhead. Each wave owns its private
// LDS segment (no __syncthreads) and processes 4 (node, quarter) units sequentially.
// Quarter->XCD pinning preserved: q = bid & 3 is constant per bid%8 residue, so each XCD
// touches only its 2 MB h-quarter (fits 4 MiB private L2). Summation order per channel is
// identical to R5 -> bit-identical output.
__global__ __launch_bounds__(256) void aggregate_k(const int* __restrict__ cnt,
                                                   const uint16_t* __restrict__ nbr,
                                                   const uint32_t* __restrict__ h2,
                                                   float* __restrict__ out) {
    const int bid  = blockIdx.x;
    const int w    = threadIdx.x >> 6;
    const int lane = threadIdx.x & 63;
    const int q    = bid & 3;            // quarter, constant per XCD (bid%8 -> XCD)
    const int k    = bid >> 2;           // 0..511

    __shared__ uint16_t jl[4][MAX_DEG];
    __shared__ float    dl[4][MAX_DEG];

    const uint32_t* hp = h2 + q * 64 + lane;     // 256 uints/row; quarter = 64 uints

    #pragma unroll
    for (int t = 0; t < 4; t++) {
        const int i = k * 16 + w * 4 + t;        // node
        int m = cnt[i]; if (m > MAX_DEG) m = MAX_DEG;

        // per-wave preload (wave-synchronous; compiler inserts lgkmcnt waits)
        for (int e = lane; e < m; e += 64) {
            uint16_t j = nbr[i * MAX_DEG + e];
            jl[w][e] = j;
            dl[w][e] = rsqrtf((float)cnt[j]);    // cnt is 32 KB -> L1/L2 resident
        }

        float s0 = 0.f, s1 = 0.f;
        #pragma unroll 8
        for (int l = 0; l < m; l++) {
            uint32_t u = hp[(int)jl[w][l] * 256];        // 256 B coalesced gather, L2-local
            float dj = dl[w][l];
            s0 += dj * __uint_as_float(u << 16);         // even channel
            s1 += dj * __uint_as_float(u & 0xFFFF0000u); // odd channel
        }
        float di = rsqrtf((float)m);
        int c = q * 128 + lane * 2;
        float2 o = {di * s0, di * s1};
        *(float2*)(out + i * OUT_C + c) = o;
    }
}

extern "C" void kernel_launch(void* const* d_in, const int* in_sizes, int n_in,
                              void* d_out, int out_size, void* d_ws, size_t ws_size,
                              hipStream_t stream) {
    const float* x  = (const float*)d_in[0];
    const int*   ei = (const int*)  d_in[1];
    const float* W  = (const float*)d_in[2];
    const float* b  = (const float*)d_in[3];
    float* out = (float*)d_out;
    char* ws = (char*)d_ws;

    // ws layout (bytes)
    const size_t CNT_OFF = 0;                       // 32 KB
    const size_t BM_OFF  = 32768;                   // 8 MB bitmap
    const size_t NBR_OFF = BM_OFF + 8388608;        // 2 MB (u16 * 8192 * 128)
    const size_t XB_OFF  = NBR_OFF + 2097152;       // 8 MB
    const size_t WB_OFF  = XB_OFF + 8388608;        // 512 KB
    const size_t H_OFF   = WB_OFF + 524288;         // 8 MB (bf16)
    int*      cnt = (int*)     (ws + CNT_OFF);
    uint32_t* bm  = (uint32_t*)(ws + BM_OFF);
    uint16_t* nbr = (uint16_t*)(ws + NBR_OFF);
    uint16_t* xb  = (uint16_t*)(ws + XB_OFF);
    uint16_t* wb  = (uint16_t*)(ws + WB_OFF);
    uint16_t* h   = (uint16_t*)(ws + H_OFF);

    convert_k<<<(X_ELEMS + W_ELEMS) / (256 * 8), 256, 0, stream>>>(x, W, xb, wb, cnt, (uint4*)bm);

    gemm_scatter_k<<<512 + (N_EDGES + N_NODES + 255) / 256, 256, 0, stream>>>(
        xb, wb, b, h, ei, cnt, nbr, bm);

    aggregate_k<<<2048, 256, 0, stream>>>(cnt, nbr, (const uint32_t*)h, out);
}

// Round 7
// 126.946 us; speedup vs baseline: 1.0841x; 1.0841x over previous
//
#include <hip/hip_runtime.h>
#include <stdint.h>

#define N_NODES 8192
#define N_EDGES 262144
#define IN_C    512
#define OUT_C   512
#define MAX_DEG 128   // raw degree Poisson(~32); max over 8192 rows ~65 (R0/R6 128-cap passed)
#define X_ELEMS (N_NODES * IN_C)                 // 4194304
#define W_ELEMS (OUT_C * IN_C)                   // 262144
#define BM_WORDS (N_NODES * (N_NODES / 32))      // 2097152 u32 = 8 MB adjacency bitmap

typedef __attribute__((ext_vector_type(8))) short short8;   // 8 bf16 in 4 VGPRs
typedef __attribute__((ext_vector_type(4))) float f32x4;

// ---- fp32 -> bf16 (RNE) ----
__device__ inline uint16_t f2bf(float f) {
    uint32_t u = __float_as_uint(f);
    uint32_t r = (u + 0x7FFFu + ((u >> 16) & 1u)) >> 16;
    return (uint16_t)r;
}

// converts x and W to bf16; also zeros degree counters and the adjacency bitmap
__global__ __launch_bounds__(256) void convert_k(const float* __restrict__ x,
                                                 const float* __restrict__ W,
                                                 uint16_t* __restrict__ xb,
                                                 uint16_t* __restrict__ wb,
                                                 int* __restrict__ cnt,
                                                 uint4* __restrict__ bm) {
    int tid = blockIdx.x * 256 + threadIdx.x;
    if (tid < N_NODES) cnt[tid] = 0;
    if (tid < BM_WORDS / 4) bm[tid] = make_uint4(0u, 0u, 0u, 0u);   // 524288 * 16B = 8 MB
    int i = tid * 8;
    const float* src; uint16_t* dst;
    if (i < X_ELEMS) { src = x + i; dst = xb + i; }
    else             { src = W + (i - X_ELEMS); dst = wb + (i - X_ELEMS); }
    float4 v0 = *(const float4*)(src);
    float4 v1 = *(const float4*)(src + 4);
    ushort4 o0, o1;
    o0.x = f2bf(v0.x); o0.y = f2bf(v0.y); o0.z = f2bf(v0.z); o0.w = f2bf(v0.w);
    o1.x = f2bf(v1.x); o1.y = f2bf(v1.y); o1.z = f2bf(v1.z); o1.w = f2bf(v1.w);
    *(ushort4*)(dst)     = o0;
    *(ushort4*)(dst + 4) = o1;
}

// ---- fused: blocks [0,256) = GEMM tiles; blocks [256,1312) = bitmap-dedup edge scatter ----
// GEMM: h = x @ W^T + b (bf16 MFMA 16x16x32, fp32 accum, bf16 out)
//   block tile 128 rows x 128 cols; wave tile 64x64 (4 A x 4 B frags -> 16 MFMA : 8 loads)
//   Operand-SWAPPED mfma(Wfrag, xfrag): D[row=quad*4+r -> out-channel n][col=l16 -> x-row m]
//   => each lane holds 4 CONSECUTIVE output channels of one row -> packed 8-B C-stores
//   XCD swizzle: the 4 ncol-blocks sharing one A-panel keep the same (bid&7) residue -> same XCD
// Scatter: atomicOr claims bit (r,c) in the 8 MB bitmap; first claimer appends c to nbr[r] and
//   bumps cnt[r] -> nbr is unique and cnt final when this kernel completes. Scatter hides under MFMA.
__global__ __launch_bounds__(256) void gemm_scatter_k(const uint16_t* __restrict__ xb,
                                                      const uint16_t* __restrict__ wb,
                                                      const float* __restrict__ bias,
                                                      uint16_t* __restrict__ h,
                                                      const int* __restrict__ ei,
                                                      int* __restrict__ cnt,
                                                      uint16_t* __restrict__ nbr,
                                                      uint32_t* __restrict__ bm) {
    const int bid = blockIdx.x;
    if (bid < 256) {
        // ---------------- GEMM path ----------------
        const int wave = threadIdx.x >> 6;
        const int lane = threadIdx.x & 63;
        const int quad = lane >> 4;
        const int l16  = lane & 15;
        // bijective (bid) -> (mrow in [0,64), ncol in [0,4)); A-panel sharers on one XCD
        const int mrow = (bid & 7) * 8 + (bid >> 5);
        const int ncol = (bid >> 3) & 3;
        const int m_base = mrow * 128 + (wave & 1) * 64;
        const int n_base = ncol * 128 + (wave >> 1) * 64;

        f32x4 acc[4][4];
        #pragma unroll
        for (int a = 0; a < 4; a++)
            #pragma unroll
            for (int s = 0; s < 4; s++) acc[a][s] = (f32x4){0.f, 0.f, 0.f, 0.f};

        #pragma unroll 2
        for (int k0 = 0; k0 < IN_C; k0 += 32) {
            short8 af[4], bf[4];
            #pragma unroll
            for (int a = 0; a < 4; a++)   // x[m=lane&15][k=quad*8+j]
                af[a] = *(const short8*)(xb + (m_base + a * 16 + l16) * IN_C + quad * 8 + k0);
            #pragma unroll
            for (int s = 0; s < 4; s++)   // W[n=lane&15][k=quad*8+j]
                bf[s] = *(const short8*)(wb + (n_base + s * 16 + l16) * IN_C + quad * 8 + k0);
            // swapped order: A-operand = W-frag, B-operand = x-frag -> D[n][m] (transposed frag)
            #pragma unroll
            for (int a = 0; a < 4; a++)
                #pragma unroll
                for (int s = 0; s < 4; s++)
                    acc[a][s] = __builtin_amdgcn_mfma_f32_16x16x32_bf16(bf[s], af[a], acc[a][s], 0, 0, 0);
        }
        // D': col=l16 -> m (x-row), row=quad*4+r -> n (out channel). 4 consecutive n per lane.
        #pragma unroll
        for (int s = 0; s < 4; s++) {
            int col_n0 = n_base + s * 16 + quad * 4;
            float4 bv = *(const float4*)(bias + col_n0);
            #pragma unroll
            for (int a = 0; a < 4; a++) {
                int row_m = m_base + a * 16 + l16;
                ushort4 o;
                o.x = f2bf(acc[a][s][0] + bv.x);
                o.y = f2bf(acc[a][s][1] + bv.y);
                o.z = f2bf(acc[a][s][2] + bv.z);
                o.w = f2bf(acc[a][s][3] + bv.w);
                *(ushort4*)(h + row_m * OUT_C + col_n0) = o;   // 8-B packed store
            }
        }
    } else {
        // ---------------- scatter path (bitmap dedup) ----------------
        int t = (bid - 256) * 256 + threadIdx.x;
        int r, c;
        if (t < N_EDGES) {
            r = ei[t];             // edge_index[0][t]
            c = ei[N_EDGES + t];   // edge_index[1][t]
        } else if (t < N_EDGES + N_NODES) {
            r = t - N_EDGES; c = r;   // self loop
        } else return;
        uint32_t w   = (uint32_t)r * (uint32_t)(N_NODES / 32) + ((uint32_t)c >> 5);
        uint32_t bit = 1u << (c & 31);
        uint32_t old = atomicOr(&bm[w], bit);
        if (!(old & bit)) {                       // first claimer of (r,c)
            int pos = atomicAdd(&cnt[r], 1);
            if (pos < MAX_DEG) nbr[r * MAX_DEG + pos] = (uint16_t)c;
        }
    }
}

// ---- out[i] = rsqrt(deg_i) * sum_j rsqrt(deg_j) * h[j]; bf16 h, channel-QUARTERED ----
// R5 structure (one 64-thread wave per (node, quarter) unit, 32768 blocks): R6's persistent
// form regressed -> reverted. q = bid & 3; under bid%8 -> XCD round-robin each XCD touches
// only its 2 MB h-quarter -> fits the private 4 MiB L2. Per-channel summation order identical.
__global__ __launch_bounds__(64) void aggregate_k(const int* __restrict__ cnt,
                                                  const uint16_t* __restrict__ nbr,
                                                  const uint32_t* __restrict__ h2,
                                                  float* __restrict__ out) {
    const int i    = blockIdx.x >> 2;
    const int q    = blockIdx.x & 3;
    const int lane = threadIdx.x;
    int m = cnt[i]; if (m > MAX_DEG) m = MAX_DEG;

    __shared__ uint16_t jl[MAX_DEG];
    __shared__ float    dl[MAX_DEG];
    for (int t = lane; t < m; t += 64) {
        uint16_t j = nbr[i * MAX_DEG + t];
        jl[t] = j;
        dl[t] = rsqrtf((float)cnt[j]);   // cnt is 32 KB -> L1/L2 resident
    }
    __syncthreads();

    const uint32_t* hp = h2 + q * 64 + lane;   // 256 uints per row; quarter = 64 uints
    float s0 = 0.f, s1 = 0.f;
    #pragma unroll 8
    for (int l = 0; l < m; l++) {
        uint32_t u = hp[(int)jl[l] * 256];                // 256 B coalesced gather, L2-local
        float dj = dl[l];
        s0 += dj * __uint_as_float(u << 16);              // even channel
        s1 += dj * __uint_as_float(u & 0xFFFF0000u);      // odd channel
    }
    float di = rsqrtf((float)m);
    int c = q * 128 + lane * 2;
    float2 o = {di * s0, di * s1};
    *(float2*)(out + i * OUT_C + c) = o;
}

extern "C" void kernel_launch(void* const* d_in, const int* in_sizes, int n_in,
                              void* d_out, int out_size, void* d_ws, size_t ws_size,
                              hipStream_t stream) {
    const float* x  = (const float*)d_in[0];
    const int*   ei = (const int*)  d_in[1];
    const float* W  = (const float*)d_in[2];
    const float* b  = (const float*)d_in[3];
    float* out = (float*)d_out;
    char* ws = (char*)d_ws;

    // ws layout (bytes)
    const size_t CNT_OFF = 0;                       // 32 KB
    const size_t BM_OFF  = 32768;                   // 8 MB bitmap
    const size_t NBR_OFF = BM_OFF + 8388608;        // 2 MB (u16 * 8192 * 128)
    const size_t XB_OFF  = NBR_OFF + 2097152;       // 8 MB
    const size_t WB_OFF  = XB_OFF + 8388608;        // 512 KB
    const size_t H_OFF   = WB_OFF + 524288;         // 8 MB (bf16)
    int*      cnt = (int*)     (ws + CNT_OFF);
    uint32_t* bm  = (uint32_t*)(ws + BM_OFF);
    uint16_t* nbr = (uint16_t*)(ws + NBR_OFF);
    uint16_t* xb  = (uint16_t*)(ws + XB_OFF);
    uint16_t* wb  = (uint16_t*)(ws + WB_OFF);
    uint16_t* h   = (uint16_t*)(ws + H_OFF);

    convert_k<<<(X_ELEMS + W_ELEMS) / (256 * 8), 256, 0, stream>>>(x, W, xb, wb, cnt, (uint4*)bm);

    gemm_scatter_k<<<256 + (N_EDGES + N_NODES + 255) / 256, 256, 0, stream>>>(
        xb, wb, b, h, ei, cnt, nbr, bm);

    aggregate_k<<<N_NODES * 4, 64, 0, stream>>>(cnt, nbr, (const uint32_t*)h, out);
}

// Round 8
// 122.538 us; speedup vs baseline: 1.1231x; 1.0360x over previous
//
#include <hip/hip_runtime.h>
#include <stdint.h>

#define N_NODES 8192
#define N_EDGES 262144
#define IN_C    512
#define OUT_C   512
#define MAX_DEG 128   // raw degree Poisson(~32); max over 8192 rows ~65 (R0/R6 128-cap passed)
#define X_ELEMS (N_NODES * IN_C)                 // 4194304
#define W_ELEMS (OUT_C * IN_C)                   // 262144
#define BM_WORDS (N_NODES * (N_NODES / 32))      // 2097152 u32 = 8 MB adjacency bitmap

typedef __attribute__((ext_vector_type(8))) short short8;   // 8 bf16 in 4 VGPRs
typedef __attribute__((ext_vector_type(4))) float f32x4;

// ---- fp32 -> bf16 (RNE) ----
__device__ inline uint16_t f2bf(float f) {
    uint32_t u = __float_as_uint(f);
    uint32_t r = (u + 0x7FFFu + ((u >> 16) & 1u)) >> 16;
    return (uint16_t)r;
}

#define GLOAD_LDS16(g, l)                                                        \
    __builtin_amdgcn_global_load_lds(                                            \
        (const __attribute__((address_space(1))) uint32_t*)(g),                  \
        (__attribute__((address_space(3))) uint32_t*)(l), 16, 0, 0)

// converts x and W to bf16; also zeros degree counters and the adjacency bitmap
__global__ __launch_bounds__(256) void convert_k(const float* __restrict__ x,
                                                 const float* __restrict__ W,
                                                 uint16_t* __restrict__ xb,
                                                 uint16_t* __restrict__ wb,
                                                 int* __restrict__ cnt,
                                                 uint4* __restrict__ bm) {
    int tid = blockIdx.x * 256 + threadIdx.x;
    if (tid < N_NODES) cnt[tid] = 0;
    if (tid < BM_WORDS / 4) bm[tid] = make_uint4(0u, 0u, 0u, 0u);   // 524288 * 16B = 8 MB
    int i = tid * 8;
    const float* src; uint16_t* dst;
    if (i < X_ELEMS) { src = x + i; dst = xb + i; }
    else             { src = W + (i - X_ELEMS); dst = wb + (i - X_ELEMS); }
    float4 v0 = *(const float4*)(src);
    float4 v1 = *(const float4*)(src + 4);
    ushort4 o0, o1;
    o0.x = f2bf(v0.x); o0.y = f2bf(v0.y); o0.z = f2bf(v0.z); o0.w = f2bf(v0.w);
    o1.x = f2bf(v1.x); o1.y = f2bf(v1.y); o1.z = f2bf(v1.z); o1.w = f2bf(v1.w);
    *(ushort4*)(dst)     = o0;
    *(ushort4*)(dst + 4) = o1;
}

// ---- fused: blocks [0,256) = GEMM tiles; blocks [256,1312) = bitmap-dedup edge scatter ----
// GEMM: h = x @ W^T + b (bf16 MFMA 16x16x32, fp32 accum, bf16 out)
//   m97-lite structure: 128x128 tile, BK=64, LDS-staged via global_load_lds width=16
//   (16 wave-instructions stage both 16-KB slabs; ds_read_b128 feeds MFMA at 2:1).
//   wave tile 64x64 (4x4 frags, 32 MFMA / 16 ds_read per K-step per wave).
//   Operand-SWAPPED mfma(Wfrag, xfrag): lane holds 4 consecutive out-channels -> 8-B C-stores
//   XCD swizzle: the 4 ncol-blocks sharing one A-panel keep the same (bid&7) residue -> same XCD
// Scatter: atomicOr claims bit (r,c) in the 8 MB bitmap; first claimer appends c to nbr[r] and
//   bumps cnt[r] -> nbr is unique and cnt final when this kernel completes. Scatter hides under MFMA.
__global__ __launch_bounds__(256) void gemm_scatter_k(const uint16_t* __restrict__ xb,
                                                      const uint16_t* __restrict__ wb,
                                                      const float* __restrict__ bias,
                                                      uint16_t* __restrict__ h,
                                                      const int* __restrict__ ei,
                                                      int* __restrict__ cnt,
                                                      uint16_t* __restrict__ nbr,
                                                      uint32_t* __restrict__ bm) {
    __shared__ uint16_t lA[128 * 64];   // 16 KB, linear [row][k]
    __shared__ uint16_t lB[128 * 64];   // 16 KB
    const int bid = blockIdx.x;
    if (bid < 256) {
        // ---------------- GEMM path ----------------
        const int wave = threadIdx.x >> 6;
        const int lane = threadIdx.x & 63;
        const int quad = lane >> 4;
        const int l16  = lane & 15;
        // bijective (bid) -> (mrow in [0,64), ncol in [0,4)); A-panel sharers on one XCD
        const int mrow = (bid & 7) * 8 + (bid >> 5);
        const int ncol = (bid >> 3) & 3;
        const int m0 = mrow * 128;            // block row base
        const int n0 = ncol * 128;            // block col (out-channel) base
        const int wm = wave & 1;              // wave m-half
        const int wn = wave >> 1;             // wave n-half

        // staging geometry: each global_load_lds_dwordx4 = 64 lanes x 16 B = 1 KB = 8 rows
        const int srow = wave * 32 + (lane >> 3);       // staged row (this lane's slot), +8 per it
        const int scol = (lane & 7) * 8;                // staged k-offset (elements)
        uint16_t* lAdst = &lA[wave * 32 * 64];          // wave-uniform LDS base, +8*64 per it
        uint16_t* lBdst = &lB[wave * 32 * 64];

        f32x4 acc[4][4];
        #pragma unroll
        for (int a = 0; a < 4; a++)
            #pragma unroll
            for (int s = 0; s < 4; s++) acc[a][s] = (f32x4){0.f, 0.f, 0.f, 0.f};

        for (int k0 = 0; k0 < IN_C; k0 += 64) {
            // ---- stage A+B K-slabs (4 x 1 KB per wave each) ----
            #pragma unroll
            for (int it = 0; it < 4; it++) {
                GLOAD_LDS16(xb + (m0 + srow + it * 8) * IN_C + k0 + scol, lAdst + it * 8 * 64);
                GLOAD_LDS16(wb + (n0 + srow + it * 8) * IN_C + k0 + scol, lBdst + it * 8 * 64);
            }
            __syncthreads();   // compiler drains vmcnt(0) before s_barrier (m97 behavior)
            // ---- compute: 2 k-halves x 16 MFMA ----
            #pragma unroll
            for (int kk = 0; kk < 2; kk++) {
                short8 af[4], bfr[4];
                #pragma unroll
                for (int a = 0; a < 4; a++)
                    af[a] = *(const short8*)&lA[(wm * 64 + a * 16 + l16) * 64 + kk * 32 + quad * 8];
                #pragma unroll
                for (int s = 0; s < 4; s++)
                    bfr[s] = *(const short8*)&lB[(wn * 64 + s * 16 + l16) * 64 + kk * 32 + quad * 8];
                #pragma unroll
                for (int a = 0; a < 4; a++)
                    #pragma unroll
                    for (int s = 0; s < 4; s++)
                        acc[a][s] = __builtin_amdgcn_mfma_f32_16x16x32_bf16(bfr[s], af[a], acc[a][s], 0, 0, 0);
            }
            __syncthreads();
        }
        // D': col=l16 -> m (x-row), row=quad*4+r -> n (out channel). 4 consecutive n per lane.
        const int m_base = m0 + wm * 64;
        const int n_base = n0 + wn * 64;
        #pragma unroll
        for (int s = 0; s < 4; s++) {
            int col_n0 = n_base + s * 16 + quad * 4;
            float4 bv = *(const float4*)(bias + col_n0);
            #pragma unroll
            for (int a = 0; a < 4; a++) {
                int row_m = m_base + a * 16 + l16;
                ushort4 o;
                o.x = f2bf(acc[a][s][0] + bv.x);
                o.y = f2bf(acc[a][s][1] + bv.y);
                o.z = f2bf(acc[a][s][2] + bv.z);
                o.w = f2bf(acc[a][s][3] + bv.w);
                *(ushort4*)(h + row_m * OUT_C + col_n0) = o;   // 8-B packed store
            }
        }
    } else {
        // ---------------- scatter path (bitmap dedup) ----------------
        int t = (bid - 256) * 256 + threadIdx.x;
        int r, c;
        if (t < N_EDGES) {
            r = ei[t];             // edge_index[0][t]
            c = ei[N_EDGES + t];   // edge_index[1][t]
        } else if (t < N_EDGES + N_NODES) {
            r = t - N_EDGES; c = r;   // self loop
        } else return;
        uint32_t w   = (uint32_t)r * (uint32_t)(N_NODES / 32) + ((uint32_t)c >> 5);
        uint32_t bit = 1u << (c & 31);
        uint32_t old = atomicOr(&bm[w], bit);
        if (!(old & bit)) {                       // first claimer of (r,c)
            int pos = atomicAdd(&cnt[r], 1);
            if (pos < MAX_DEG) nbr[r * MAX_DEG + pos] = (uint16_t)c;
        }
    }
}

// ---- out[i] = rsqrt(deg_i) * sum_j rsqrt(deg_j) * h[j]; bf16 h, channel-QUARTERED ----
// R5 structure (one 64-thread wave per (node, quarter) unit, 32768 blocks). q = bid & 3;
// under bid%8 -> XCD round-robin each XCD touches only its 2 MB h-quarter -> fits the
// private 4 MiB L2. Per-channel summation order identical.
__global__ __launch_bounds__(64) void aggregate_k(const int* __restrict__ cnt,
                                                  const uint16_t* __restrict__ nbr,
                                                  const uint32_t* __restrict__ h2,
                                                  float* __restrict__ out) {
    const int i    = blockIdx.x >> 2;
    const int q    = blockIdx.x & 3;
    const int lane = threadIdx.x;
    int m = cnt[i]; if (m > MAX_DEG) m = MAX_DEG;

    __shared__ uint16_t jl[MAX_DEG];
    __shared__ float    dl[MAX_DEG];
    for (int t = lane; t < m; t += 64) {
        uint16_t j = nbr[i * MAX_DEG + t];
        jl[t] = j;
        dl[t] = rsqrtf((float)cnt[j]);   // cnt is 32 KB -> L1/L2 resident
    }
    __syncthreads();

    const uint32_t* hp = h2 + q * 64 + lane;   // 256 uints per row; quarter = 64 uints
    float s0 = 0.f, s1 = 0.f;
    #pragma unroll 8
    for (int l = 0; l < m; l++) {
        uint32_t u = hp[(int)jl[l] * 256];                // 256 B coalesced gather, L2-local
        float dj = dl[l];
        s0 += dj * __uint_as_float(u << 16);              // even channel
        s1 += dj * __uint_as_float(u & 0xFFFF0000u);      // odd channel
    }
    float di = rsqrtf((float)m);
    int c = q * 128 + lane * 2;
    float2 o = {di * s0, di * s1};
    *(float2*)(out + i * OUT_C + c) = o;
}

extern "C" void kernel_launch(void* const* d_in, const int* in_sizes, int n_in,
                              void* d_out, int out_size, void* d_ws, size_t ws_size,
                              hipStream_t stream) {
    const float* x  = (const float*)d_in[0];
    const int*   ei = (const int*)  d_in[1];
    const float* W  = (const float*)d_in[2];
    const float* b  = (const float*)d_in[3];
    float* out = (float*)d_out;
    char* ws = (char*)d_ws;

    // ws layout (bytes)
    const size_t CNT_OFF = 0;                       // 32 KB
    const size_t BM_OFF  = 32768;                   // 8 MB bitmap
    const size_t NBR_OFF = BM_OFF + 8388608;        // 2 MB (u16 * 8192 * 128)
    const size_t XB_OFF  = NBR_OFF + 2097152;       // 8 MB
    const size_t WB_OFF  = XB_OFF + 8388608;        // 512 KB
    const size_t H_OFF   = WB_OFF + 524288;         // 8 MB (bf16)
    int*      cnt = (int*)     (ws + CNT_OFF);
    uint32_t* bm  = (uint32_t*)(ws + BM_OFF);
    uint16_t* nbr = (uint16_t*)(ws + NBR_OFF);
    uint16_t* xb  = (uint16_t*)(ws + XB_OFF);
    uint16_t* wb  = (uint16_t*)(ws + WB_OFF);
    uint16_t* h   = (uint16_t*)(ws + H_OFF);

    convert_k<<<(X_ELEMS + W_ELEMS) / (256 * 8), 256, 0, stream>>>(x, W, xb, wb, cnt, (uint4*)bm);

    gemm_scatter_k<<<256 + (N_EDGES + N_NODES + 255) / 256, 256, 0, stream>>>(
        xb, wb, b, h, ei, cnt, nbr, bm);

    aggregate_k<<<N_NODES * 4, 64, 0, stream>>>(cnt, nbr, (const uint32_t*)h, out);
}

// Round 9
// 119.726 us; speedup vs baseline: 1.1495x; 1.0235x over previous
//
#include <hip/hip_runtime.h>
#include <stdint.h>

#define N_NODES 8192
#define N_EDGES 262144
#define IN_C    512
#define OUT_C   512
#define MAX_DEG 128   // raw degree Poisson(~32); max over 8192 rows ~65 (R0/R6 128-cap passed)
#define W_ELEMS (OUT_C * IN_C)                   // 262144
#define BM_WORDS (N_NODES * (N_NODES / 32))      // 2097152 u32 = 8 MB adjacency bitmap

typedef __attribute__((ext_vector_type(8))) short short8;   // 8 bf16 in 4 VGPRs
typedef __attribute__((ext_vector_type(4))) float f32x4;

// ---- fp32 -> bf16 (RNE) ----
__device__ inline uint16_t f2bf(float f) {
    uint32_t u = __float_as_uint(f);
    uint32_t r = (u + 0x7FFFu + ((u >> 16) & 1u)) >> 16;
    return (uint16_t)r;
}

#define GLOAD_LDS16(g, l)                                                        \
    __builtin_amdgcn_global_load_lds(                                            \
        (const __attribute__((address_space(1))) uint32_t*)(g),                  \
        (__attribute__((address_space(3))) uint32_t*)(l), 16, 0, 0)

// W -> bf16; zero degree counters and the adjacency bitmap. (x is no longer pre-converted:
// the GEMM converts its own A-slabs in-register, killing the 25 MB xb round-trip.)
__global__ __launch_bounds__(256) void convert_k(const float* __restrict__ W,
                                                 uint16_t* __restrict__ wb,
                                                 int* __restrict__ cnt,
                                                 uint4* __restrict__ bm) {
    int tid = blockIdx.x * 256 + threadIdx.x;            // 2048 blocks * 256 = 524288
    if (tid < N_NODES) cnt[tid] = 0;
    bm[tid] = make_uint4(0u, 0u, 0u, 0u);                // 524288 * 16B = 8 MB
    if (tid < W_ELEMS / 8) {
        int i = tid * 8;
        float4 v0 = *(const float4*)(W + i);
        float4 v1 = *(const float4*)(W + i + 4);
        ushort4 o0, o1;
        o0.x = f2bf(v0.x); o0.y = f2bf(v0.y); o0.z = f2bf(v0.z); o0.w = f2bf(v0.w);
        o1.x = f2bf(v1.x); o1.y = f2bf(v1.y); o1.z = f2bf(v1.z); o1.w = f2bf(v1.w);
        *(ushort4*)(wb + i)     = o0;
        *(ushort4*)(wb + i + 4) = o1;
    }
}

// ---- fused: blocks [0,256) = GEMM tiles; blocks [256,1312) = bitmap-dedup edge scatter ----
// GEMM: h = x @ W^T + b (bf16 MFMA 16x16x32, fp32 accum, bf16 out)
//   128x128 tile, BK=64. B-slab: global_load_lds width=16 from pre-converted wb.
//   A-slab: reg-staged from fp32 x with in-register f2bf (8 float4 loads + cvt + ds_write_b64
//   per lane per K-step) -> x never round-trips through a bf16 buffer. VALU cvt co-issues
//   with MFMA (separate pipes); scatter blocks fill remaining stalls.
//   Operand-SWAPPED mfma(Wfrag, xfrag): lane holds 4 consecutive out-channels -> 8-B C-stores
//   XCD swizzle: the 4 ncol-blocks sharing one A-panel keep the same (bid&7) residue -> same XCD
// Scatter: atomicOr claims bit (r,c) in the 8 MB bitmap; first claimer appends c to nbr[r] and
//   bumps cnt[r] -> nbr is unique and cnt final when this kernel completes.
__global__ __launch_bounds__(256) void gemm_scatter_k(const float* __restrict__ x,
                                                      const uint16_t* __restrict__ wb,
                                                      const float* __restrict__ bias,
                                                      uint16_t* __restrict__ h,
                                                      const int* __restrict__ ei,
                                                      int* __restrict__ cnt,
                                                      uint16_t* __restrict__ nbr,
                                                      uint32_t* __restrict__ bm) {
    __shared__ uint16_t lA[128 * 64];   // 16 KB, linear [row][k]
    __shared__ uint16_t lB[128 * 64];   // 16 KB
    const int bid = blockIdx.x;
    if (bid < 256) {
        // ---------------- GEMM path ----------------
        const int wave = threadIdx.x >> 6;
        const int lane = threadIdx.x & 63;
        const int quad = lane >> 4;
        const int l16  = lane & 15;
        // bijective (bid) -> (mrow in [0,64), ncol in [0,4)); A-panel sharers on one XCD
        const int mrow = (bid & 7) * 8 + (bid >> 5);
        const int ncol = (bid >> 3) & 3;
        const int m0 = mrow * 128;            // block row base
        const int n0 = ncol * 128;            // block col (out-channel) base
        const int wm = wave & 1;              // wave m-half
        const int wn = wave >> 1;             // wave n-half

        // B staging geometry: each global_load_lds_dwordx4 = 64 lanes x 16 B = 1 KB = 8 rows
        const int srow = wave * 32 + (lane >> 3);       // staged row, +8 per it
        const int scol = (lane & 7) * 8;                // staged k-offset (elements)
        uint16_t* lBdst = &lB[wave * 32 * 64];          // wave-uniform LDS base

        // A staging geometry: 8 rounds x 4 rows; lane covers (row = rnd*4 + lane>>4, 4 k-elems)
        const int arow = lane >> 4;                     // 0..3
        const int acol = (lane & 15) * 4;               // 0..60

        f32x4 acc[4][4];
        #pragma unroll
        for (int a = 0; a < 4; a++)
            #pragma unroll
            for (int s = 0; s < 4; s++) acc[a][s] = (f32x4){0.f, 0.f, 0.f, 0.f};

        for (int k0 = 0; k0 < IN_C; k0 += 64) {
            // ---- issue B-slab gload_lds (4 x 1 KB per wave) ----
            #pragma unroll
            for (int it = 0; it < 4; it++)
                GLOAD_LDS16(wb + (n0 + srow + it * 8) * IN_C + k0 + scol, lBdst + it * 8 * 64);
            // ---- A-slab: fp32 load -> bf16 cvt -> LDS ----
            float4 av[8];
            #pragma unroll
            for (int rnd = 0; rnd < 8; rnd++)
                av[rnd] = *(const float4*)(x + (size_t)(m0 + wave * 32 + rnd * 4 + arow) * IN_C
                                           + k0 + acol);
            #pragma unroll
            for (int rnd = 0; rnd < 8; rnd++) {
                ushort4 o;
                o.x = f2bf(av[rnd].x); o.y = f2bf(av[rnd].y);
                o.z = f2bf(av[rnd].z); o.w = f2bf(av[rnd].w);
                *(ushort4*)&lA[(wave * 32 + rnd * 4 + arow) * 64 + acol] = o;
            }
            __syncthreads();   // drains vmcnt (B gloads) + lgkm (A ds_writes)
            // ---- compute: 2 k-halves x 16 MFMA ----
            #pragma unroll
            for (int kk = 0; kk < 2; kk++) {
                short8 af[4], bfr[4];
                #pragma unroll
                for (int a = 0; a < 4; a++)
                    af[a] = *(const short8*)&lA[(wm * 64 + a * 16 + l16) * 64 + kk * 32 + quad * 8];
                #pragma unroll
                for (int s = 0; s < 4; s++)
                    bfr[s] = *(const short8*)&lB[(wn * 64 + s * 16 + l16) * 64 + kk * 32 + quad * 8];
                #pragma unroll
                for (int a = 0; a < 4; a++)
                    #pragma unroll
                    for (int s = 0; s < 4; s++)
                        acc[a][s] = __builtin_amdgcn_mfma_f32_16x16x32_bf16(bfr[s], af[a], acc[a][s], 0, 0, 0);
            }
            __syncthreads();
        }
        // D': col=l16 -> m (x-row), row=quad*4+r -> n (out channel). 4 consecutive n per lane.
        const int m_base = m0 + wm * 64;
        const int n_base = n0 + wn * 64;
        #pragma unroll
        for (int s = 0; s < 4; s++) {
            int col_n0 = n_base + s * 16 + quad * 4;
            float4 bv = *(const float4*)(bias + col_n0);
            #pragma unroll
            for (int a = 0; a < 4; a++) {
                int row_m = m_base + a * 16 + l16;
                ushort4 o;
                o.x = f2bf(acc[a][s][0] + bv.x);
                o.y = f2bf(acc[a][s][1] + bv.y);
                o.z = f2bf(acc[a][s][2] + bv.z);
                o.w = f2bf(acc[a][s][3] + bv.w);
                *(ushort4*)(h + row_m * OUT_C + col_n0) = o;   // 8-B packed store
            }
        }
    } else {
        // ---------------- scatter path (bitmap dedup) ----------------
        int t = (bid - 256) * 256 + threadIdx.x;
        int r, c;
        if (t < N_EDGES) {
            r = ei[t];             // edge_index[0][t]
            c = ei[N_EDGES + t];   // edge_index[1][t]
        } else if (t < N_EDGES + N_NODES) {
            r = t - N_EDGES; c = r;   // self loop
        } else return;
        uint32_t w   = (uint32_t)r * (uint32_t)(N_NODES / 32) + ((uint32_t)c >> 5);
        uint32_t bit = 1u << (c & 31);
        uint32_t old = atomicOr(&bm[w], bit);
        if (!(old & bit)) {                       // first claimer of (r,c)
            int pos = atomicAdd(&cnt[r], 1);
            if (pos < MAX_DEG) nbr[r * MAX_DEG + pos] = (uint16_t)c;
        }
    }
}

// ---- out[i] = rsqrt(deg_i) * sum_j rsqrt(deg_j) * h[j]; bf16 h, channel-QUARTERED ----
// R5 structure (one 64-thread wave per (node, quarter) unit, 32768 blocks). q = bid & 3;
// under bid%8 -> XCD round-robin each XCD touches only its 2 MB h-quarter -> fits the
// private 4 MiB L2. Per-channel summation order identical.
__global__ __launch_bounds__(64) void aggregate_k(const int* __restrict__ cnt,
                                                  const uint16_t* __restrict__ nbr,
                                                  const uint32_t* __restrict__ h2,
                                                  float* __restrict__ out) {
    const int i    = blockIdx.x >> 2;
    const int q    = blockIdx.x & 3;
    const int lane = threadIdx.x;
    int m = cnt[i]; if (m > MAX_DEG) m = MAX_DEG;

    __shared__ uint16_t jl[MAX_DEG];
    __shared__ float    dl[MAX_DEG];
    for (int t = lane; t < m; t += 64) {
        uint16_t j = nbr[i * MAX_DEG + t];
        jl[t] = j;
        dl[t] = rsqrtf((float)cnt[j]);   // cnt is 32 KB -> L1/L2 resident
    }
    __syncthreads();

    const uint32_t* hp = h2 + q * 64 + lane;   // 256 uints per row; quarter = 64 uints
    float s0 = 0.f, s1 = 0.f;
    #pragma unroll 8
    for (int l = 0; l < m; l++) {
        uint32_t u = hp[(int)jl[l] * 256];                // 256 B coalesced gather, L2-local
        float dj = dl[l];
        s0 += dj * __uint_as_float(u << 16);              // even channel
        s1 += dj * __uint_as_float(u & 0xFFFF0000u);      // odd channel
    }
    float di = rsqrtf((float)m);
    int c = q * 128 + lane * 2;
    float2 o = {di * s0, di * s1};
    *(float2*)(out + i * OUT_C + c) = o;
}

extern "C" void kernel_launch(void* const* d_in, const int* in_sizes, int n_in,
                              void* d_out, int out_size, void* d_ws, size_t ws_size,
                              hipStream_t stream) {
    const float* x  = (const float*)d_in[0];
    const int*   ei = (const int*)  d_in[1];
    const float* W  = (const float*)d_in[2];
    const float* b  = (const float*)d_in[3];
    float* out = (float*)d_out;
    char* ws = (char*)d_ws;

    // ws layout (bytes)
    const size_t CNT_OFF = 0;                       // 32 KB
    const size_t BM_OFF  = 32768;                   // 8 MB bitmap
    const size_t NBR_OFF = BM_OFF + 8388608;        // 2 MB (u16 * 8192 * 128)
    const size_t WB_OFF  = NBR_OFF + 2097152;       // 512 KB
    const size_t H_OFF   = WB_OFF + 524288;         // 8 MB (bf16)
    int*      cnt = (int*)     (ws + CNT_OFF);
    uint32_t* bm  = (uint32_t*)(ws + BM_OFF);
    uint16_t* nbr = (uint16_t*)(ws + NBR_OFF);
    uint16_t* wb  = (uint16_t*)(ws + WB_OFF);
    uint16_t* h   = (uint16_t*)(ws + H_OFF);

    convert_k<<<BM_WORDS / 4 / 256, 256, 0, stream>>>(W, wb, cnt, (uint4*)bm);

    gemm_scatter_k<<<256 + (N_EDGES + N_NODES + 255) / 256, 256, 0, stream>>>(
        x, wb, b, h, ei, cnt, nbr, bm);

    aggregate_k<<<N_NODES * 4, 64, 0, stream>>>(cnt, nbr, (const uint32_t*)h, out);
}